// Round 16
// baseline (342.820 us; speedup 1.0000x reference)
//
#include <hip/hip_runtime.h>
#include <hip/hip_bf16.h>
#include <hip/hip_fp16.h>

typedef __half h16;
typedef _Float16 f16;
typedef f16 f16x8 __attribute__((ext_vector_type(8)));
typedef __attribute__((ext_vector_type(4))) float f32x4;

#define NB 4
#define NCH 64
#define HW 2304      // 48*48
#define NP 7470      // total patches across 5 scales
#define NPAD 7552    // 59*128 = 236*32
#define NT 236       // k-tiles of 32
#define NT2 118      // per K-split half
#define NBLK 59      // 128-col blocks
#define SW2 NPAD
#define TOTU (NB*HW*288)

__device__ __forceinline__ float us2f(unsigned short u){
  unsigned v = (unsigned)u << 16; float f; __builtin_memcpy(&f, &v, 4); return f;
}
__device__ __forceinline__ float ldf(const void* p, size_t i, int f){
  return f ? us2f(((const unsigned short*)p)[i]) : ((const float*)p)[i];
}
__device__ __forceinline__ void gl16(const void* g, void* l){
  __builtin_amdgcn_global_load_lds((const __attribute__((address_space(1))) unsigned int*)g,
                                   (__attribute__((address_space(3))) unsigned int*)l, 16, 0, 0);
}

// full decode (divides) — used ONLY by k_lut
__device__ __forceinline__ void n_decode(int n, int& off, int& d, int& y, int& x){
  if (n < 2304)      { off = 0;    d = 48; }
  else if (n < 4153) { off = 2304; d = 43; }
  else if (n < 5597) { off = 4153; d = 38; }
  else if (n < 6686) { off = 5597; d = 33; }
  else               { off = 6686; d = 28; }
  int l = n - off; y = l / d; x = l - y * d;
}
// div-free range lookup
__device__ __forceinline__ void n_range(int n, int& off, int& d){
  if (n < 2304)      { off = 0;    d = 48; }
  else if (n < 4153) { off = 2304; d = 43; }
  else if (n < 5597) { off = 4153; d = 38; }
  else if (n < 6686) { off = 5597; d = 33; }
  else               { off = 6686; d = 28; }
}

// ---- LUT: lut[n] = (y, x) ----
__global__ __launch_bounds__(256) void k_lut(ushort2* __restrict__ lut){
  int n = blockIdx.x * 256 + threadIdx.x;
  if (n >= NP) return;
  int off, d, y, x; n_decode(n, off, d, y, x);
  lut[n] = make_ushort2((unsigned short)y, (unsigned short)x);
}

// ---- dtype probe (proven R3-R15) ----
__global__ __launch_bounds__(256) void k_detect(const void* __restrict__ x, int* __restrict__ flag){
  const unsigned short* u = (const unsigned short*)x;
  int tid = threadIdx.x;
  int c = 0;
  for (int i = tid; i < 8192; i += 256){
    float v = us2f(u[i]);
    float a = fabsf(v);
    if (v == 0.f || (a > 1e-5f && a < 1e3f)) c++;
  }
  #pragma unroll
  for (int o = 1; o < 64; o <<= 1) c += __shfl_xor(c, o);
  __shared__ int wr[4];
  if ((tid & 63) == 0) wr[tid >> 6] = c;
  __syncthreads();
  if (tid == 0) flag[0] = ((wr[0]+wr[1]+wr[2]+wr[3]) > 7000) ? 1 : 0;
}

struct CanonArgs { const void* src[9]; float* dst[9]; int end[9]; };

__global__ __launch_bounds__(256) void k_canon_all(CanonArgs a, int tot, const int* __restrict__ flag){
  int id = blockIdx.x * 256 + threadIdx.x;
  if (id >= tot) return;
  int k = 0;
  while (id >= a.end[k]) k++;
  int local = id - (k ? a.end[k-1] : 0);
  float v;
  if (flag[0]) v = us2f(((const unsigned short*)a.src[k])[local]);
  else         v = ((const float*)a.src[k])[local];
  a.dst[k][local] = v;
}

// Bilinear resize from RAW x (flag-dispatched dtype): xs f16 [b][c][n]
__global__ __launch_bounds__(256) void k_resize(const void* __restrict__ xraw, const int* __restrict__ flag,
                                                const ushort2* __restrict__ lut, h16* __restrict__ xs){
  int id = blockIdx.x * 256 + threadIdx.x;
  if (id >= NB * NCH * NP) return;
  int f = flag[0];
  int b = id / (NCH*NP), rem = id - b*(NCH*NP);
  int c = rem / NP, n = rem - c*NP;
  int off, d; n_range(n, off, d);
  ushort2 yx = lut[n];
  int y = yx.x, xx = yx.y;
  size_t base = ((size_t)b * NCH + c) * HW;
  float v;
  if (off == 0){
    v = ldf(xraw, base + y*48 + xx, f);
  } else {
    float cy = (y + 0.5f) * (48.0f / (float)d) - 0.5f;
    float cx = (xx + 0.5f) * (48.0f / (float)d) - 0.5f;
    int y0 = (int)floorf(cy), x0 = (int)floorf(cx);
    float fy = cy - (float)y0, fx = cx - (float)x0;
    int y1 = min(y0 + 1, 47), x1 = min(x0 + 1, 47);
    y0 = max(y0, 0); x0 = max(x0, 0);
    v = (1.f-fy)*((1.f-fx)*ldf(xraw, base + y0*48+x0, f) + fx*ldf(xraw, base + y0*48+x1, f))
      + fy*((1.f-fx)*ldf(xraw, base + y1*48+x0, f) + fx*ldf(xraw, base + y1*48+x1, f));
  }
  xs[id] = __float2half(v);
}

// All three 1x1 convs in one launch; z selects {mat, baseh, mbuf}.
struct ConvArgs {
  const float* W[3]; const float* bias[3]; const float* alpha[3];
  void* out[3]; int npix[3]; int cout[3]; size_t ob[3]; int rso[3]; int of16[3];
};
__global__ __launch_bounds__(256) void k_conv_all(const h16* __restrict__ xs, ConvArgs ca){
  int z = blockIdx.z;
  int npix = ca.npix[z], cout = ca.cout[z];
  int n0 = blockIdx.x * 64;
  if (n0 >= npix) return;
  __shared__ float Wl[64*64];
  __shared__ float it[64][64];
  int b = blockIdx.y;
  int tid = threadIdx.x;
  const h16* ib = xs + (size_t)b * (64*NP);
  const float* Wt = ca.W[z];
  for (int i = tid; i < cout * 64; i += 256) Wl[i] = Wt[i];
  for (int i = tid; i < 64 * 64; i += 256){
    int ci = i >> 6, nn = i & 63;
    int n = n0 + nn;
    it[ci][nn] = (n < npix) ? __half2float(ib[(size_t)ci * NP + n]) : 0.f;
  }
  __syncthreads();
  float al = ca.alpha[z][0];
  const float* bias = ca.bias[z];
  for (int oi = tid; oi < cout * 64; oi += 256){
    int co = oi >> 6, nn = oi & 63;
    float acc = bias[co];
    #pragma unroll
    for (int ci = 0; ci < 64; ci++) acc = fmaf(Wl[co*64+ci], it[ci][nn], acc);
    acc = acc >= 0.f ? acc : al * acc;
    int n = n0 + nn;
    if (n < npix){
      size_t idx = (size_t)b * ca.ob[z] + (size_t)co * ca.rso[z] + n;
      if (ca.of16[z]) ((h16*)ca.out[z])[idx] = __float2half(acc);
      else            ((float*)ca.out[z])[idx] = acc;
    }
  }
}

// pass 1: q[b][n] = sum_c mat[c][n]^2
__global__ __launch_bounds__(256) void k_sq(const float* __restrict__ mat, float* __restrict__ q){
  int id = blockIdx.x * 256 + threadIdx.x;
  if (id >= NB * NP) return;
  int b = id / NP, n = id - b * NP;
  const float* mp = mat + (size_t)b * 32 * NP + n;
  float s = 0.f;
  #pragma unroll
  for (int c = 0; c < 32; c++){ float v = mp[(size_t)c * NP]; s += v * v; }
  q[id] = s;
}

// pass 2: ninv[b][n] = 1/max(sqrt(9-tap sum of q), 1e-4); LUT decode
__global__ __launch_bounds__(256) void k_ninv(const float* __restrict__ q, float* __restrict__ ninv,
                                              const ushort2* __restrict__ lut){
  int id = blockIdx.x * 256 + threadIdx.x;
  if (id >= NB * NP) return;
  int b = id / NP, n = id - b * NP;
  int off, d; n_range(n, off, d);
  ushort2 yx = lut[n];
  int y = yx.x, x = yx.y;
  const float* qb = q + (size_t)b * NP + off;
  float s = 0.f;
  #pragma unroll
  for (int dy = -1; dy <= 1; dy++){
    int yy = y + dy; if (yy < 0 || yy >= d) continue;
    #pragma unroll
    for (int dx = -1; dx <= 1; dx++){
      int xx = x + dx; if (xx < 0 || xx >= d) continue;
      s += qb[yy * d + xx];
    }
  }
  ninv[id] = 1.f / fmaxf(sqrtf(s), 1e-4f);
}

// fused packU + packR (id-partitioned); LUT decode in packR.
__global__ __launch_bounds__(256) void k_packUR(const float* __restrict__ mbuf, const h16* __restrict__ baseh,
    const ushort2* __restrict__ lut, h16* __restrict__ U, h16* __restrict__ RpT){
  int id = blockIdx.x * 256 + threadIdx.x;
  if (id < TOTU){
    int b = id / (HW*288), rem = id - b*(HW*288);
    int p = rem / 288, k = rem - p * 288;
    int c = k / 9, r = k - c * 9, kh = r / 3, kw = r - kh * 3;
    int y = p / 48 + kh - 1, x = (p % 48) + kw - 1;
    float v = 0.f;
    if (y >= 0 && y < 48 && x >= 0 && x < 48)
      v = mbuf[((size_t)b * 32 + c) * HW + y * 48 + x];
    U[id] = __float2half(v);
    return;
  }
  int id2 = id - TOTU;
  if (id2 >= NB * NT * 576 * 32) return;
  int b = id2 / (NT*576*32), rem = id2 - b*(NT*576*32);
  int t = rem / (576*32), rem2 = rem - t*(576*32);
  int j = rem2 / 32, kl = rem2 - j*32;
  int n = t*32 + kl;
  h16 v = __float2half(0.f);
  if (n < NP){
    int c = j / 9, r = j - c * 9, kh = r / 3, kw = r - kh * 3;
    int off, d; n_range(n, off, d);
    ushort2 yx = lut[n];
    int yy = (int)yx.x + kh - 1, xx = (int)yx.y + kw - 1;
    if (yy >= 0 && yy < d && xx >= 0 && xx < d)
      v = baseh[((size_t)b * 64 + c) * NP + off + yy * d + xx];
  }
  RpT[id2] = v;
}

// unfold mat * (10*ninv) -> Wp[g][NPAD][288] f16; LUT decode
__global__ __launch_bounds__(256) void k_packW(const float* __restrict__ mat, const float* __restrict__ ninv,
                                               const ushort2* __restrict__ lut, h16* __restrict__ Wp, int b0, int g){
  int id = blockIdx.x * 256 + threadIdx.x;
  if (id >= g * NPAD * 288) return;
  int bg = id / (NPAD*288), rem = id - bg*(NPAD*288);
  int n = rem / 288, k = rem - n * 288;
  float v = 0.f;
  if (n < NP){
    int b = b0 + bg;
    int c = k / 9, r = k - c * 9, kh = r / 3, kw = r - kh * 3;
    int off, d; n_range(n, off, d);
    ushort2 yx = lut[n];
    int yy = (int)yx.x + kh - 1, xx = (int)yx.y + kw - 1;
    if (yy >= 0 && yy < d && xx >= 0 && xx < d)
      v = mat[((size_t)b * 32 + c) * NP + off + yy * d + xx] * 10.f * ninv[(size_t)b*NP + n];
  }
  Wp[id] = __float2half(v);
}

// GEMM1 + fused block-local softmax stats.
// 256 thr, 4 waves (2wm x 2wn), wave tile 64x64 = 4mt x 4nt (0.5 reads/MFMA);
// 3-deep counted-vmcnt pipeline (4 gl16/thr/tile -> vmcnt 8/4/0);
// XCD-chunked 1D grid; setprio; LDS-staged coalesced S16 epilogue.
__global__ __launch_bounds__(256) void k_gemm1m(const f16* __restrict__ U, const f16* __restrict__ Wp,
    h16* __restrict__ S16, float* __restrict__ Pm, float* __restrict__ Ps, int b0){
  int nwg = gridDim.x;
  int p = blockIdx.x;
  int qc = nwg >> 3, rc = nwg & 7, xcd = p & 7;
  int L = (xcd < rc ? xcd*(qc+1) : rc*(qc+1) + (xcd - rc)*qc) + (p >> 3);
  int my = L % 18; int t1 = L / 18; int nb = t1 % NBLK; int bg = t1 / NBLK;
  int b = b0 + bg;
  int m0 = my * 128, n0 = nb * 128;
  int tid = threadIdx.x, l = tid & 63, w = tid >> 6;
  int wm = w >> 1, wn = w & 1;
  int ch = l >> 4, cl = l & 15;
  __shared__ __align__(16) char smem[51200];
  // At[t]=smem+t*8192 (t<3); Bt[t]=smem+24576+t*8192; mred@49152; sred@50176.
  // Epilogue: Tl (h16 [128][132]) aliases smem+0 (33792B).
  float* mredp = (float*)(smem + 49152);
  float* sredp = (float*)(smem + 50176);
  f32x4 acc[4][4] = {};
  const f16* Ub = U + ((size_t)b * HW + m0) * 288;
  const f16* Wb = Wp + ((size_t)bg * NPAD + n0) * 288;
  int abyte[4], bbyte[4];
  #pragma unroll
  for (int mt = 0; mt < 4; mt++){
    int lr = wm*64 + mt*16 + cl;
    abyte[mt] = lr*64 + ((ch ^ ((lr>>1)&3))<<4);
  }
  #pragma unroll
  for (int nt = 0; nt < 4; nt++){
    int lr = wn*64 + nt*16 + cl;
    bbyte[nt] = lr*64 + ((ch ^ ((lr>>1)&3))<<4);
  }
  auto ST1 = [&](int t, int bi){
    #pragma unroll
    for (int rep = 0; rep < 2; rep++){
      int i = tid + rep*256;
      int row = i >> 2, cs = (i & 3) ^ ((row >> 1) & 3);
      gl16(Ub + (size_t)row*288 + t*32 + cs*8, smem + bi*8192 + i*16);
      gl16(Wb + (size_t)row*288 + t*32 + cs*8, smem + 24576 + bi*8192 + i*16);
    }
  };
  ST1(0, 0);
  ST1(1, 1);
  __syncthreads();     // drains vmcnt; tiles 0,1 landed
  int cur = 0;
  for (int t = 0; t < 9; ++t){
    int nx = cur + 2; if (nx >= 3) nx -= 3;
    if (t + 2 < 9){
      ST1(t + 2, nx);
      asm volatile("s_waitcnt vmcnt(8)" ::: "memory");
    } else if (t + 1 < 9){
      asm volatile("s_waitcnt vmcnt(4)" ::: "memory");
    } else {
      asm volatile("s_waitcnt vmcnt(0)" ::: "memory");
    }
    __builtin_amdgcn_s_barrier();
    asm volatile("" ::: "memory");
    const char* Ac = smem + cur*8192;
    const char* Bc = smem + 24576 + cur*8192;
    __builtin_amdgcn_s_setprio(1);
    f16x8 a[4], bv[4];
    #pragma unroll
    for (int mt = 0; mt < 4; mt++) a[mt] = *reinterpret_cast<const f16x8*>(Ac + abyte[mt]);
    #pragma unroll
    for (int nt = 0; nt < 4; nt++) bv[nt] = *reinterpret_cast<const f16x8*>(Bc + bbyte[nt]);
    #pragma unroll
    for (int mt = 0; mt < 4; mt++)
      #pragma unroll
      for (int nt = 0; nt < 4; nt++)
        acc[mt][nt] = __builtin_amdgcn_mfma_f32_16x16x32_f16(a[mt], bv[nt], acc[mt][nt], 0, 0, 0);
    __builtin_amdgcn_s_setprio(0);
    asm volatile("s_waitcnt lgkmcnt(0)" ::: "memory");
    __builtin_amdgcn_s_barrier();
    cur = cur + 1; if (cur >= 3) cur -= 3;
  }
  // phase A: block-local row max over the 128 cols
  #pragma unroll
  for (int mt = 0; mt < 4; mt++)
    #pragma unroll
    for (int i = 0; i < 4; i++){
      float v = -3e38f;
      #pragma unroll
      for (int nt = 0; nt < 4; nt++){
        int gn = n0 + wn*64 + nt*16 + cl;
        float t = acc[mt][nt][i];
        v = fmaxf(v, (gn < NP) ? t : -3e38f);
      }
      v = fmaxf(v, __shfl_xor(v, 1));
      v = fmaxf(v, __shfl_xor(v, 2));
      v = fmaxf(v, __shfl_xor(v, 4));
      v = fmaxf(v, __shfl_xor(v, 8));
      if (cl == 0) mredp[(wm*64 + mt*16 + ch*4 + i)*2 + wn] = v;
    }
  __syncthreads();
  // phase B: exp into LDS tile (aliases At/Bt), row sums
  {
    h16* Tl = (h16*)smem;
    #pragma unroll
    for (int mt = 0; mt < 4; mt++)
      #pragma unroll
      for (int i = 0; i < 4; i++){
        int r = wm*64 + mt*16 + ch*4 + i;
        float Ml = fmaxf(mredp[r*2+0], mredp[r*2+1]);
        float s = 0.f;
        #pragma unroll
        for (int nt = 0; nt < 4; nt++){
          int c = wn*64 + nt*16 + cl;
          int gn = n0 + c;
          float e = (gn < NP) ? __expf(acc[mt][nt][i] - Ml) : 0.f;
          Tl[r*132 + c] = __float2half(e);
          s += e;
        }
        s += __shfl_xor(s, 1);
        s += __shfl_xor(s, 2);
        s += __shfl_xor(s, 4);
        s += __shfl_xor(s, 8);
        if (cl == 0) sredp[r*2 + wn] = s;
      }
  }
  __syncthreads();
  // phase C: stats out
  if (tid < 128){
    float Mf = fmaxf(mredp[tid*2+0], mredp[tid*2+1]);
    float Lg = sredp[tid*2+0] + sredp[tid*2+1];
    size_t o = ((size_t)bg*HW + m0 + tid)*NBLK + nb;
    Pm[o] = Mf; Ps[o] = Lg;
  }
  // phase D: coalesced S16 write, 128 rows x 256B = 2048 uint4; 256 thr x 8
  {
    const h16* Tl = (const h16*)smem;
    #pragma unroll
    for (int rep = 0; rep < 8; rep++){
      int idx = tid + rep*256;
      int j0 = idx >> 4, qq = idx & 15;
      uint4 v = *reinterpret_cast<const uint4*>((const char*)Tl + j0*264 + qq*16);
      h16* dst = S16 + ((size_t)bg*HW + m0 + j0)*SW2 + n0 + qq*8;
      *reinterpret_cast<uint4*>(dst) = v;
    }
  }
}

// combine partials (wave per row): Fac[bg][m][k] = exp(Mloc-Mglob)/L_glob
__global__ __launch_bounds__(256) void k_sfac(const float* __restrict__ Pm, const float* __restrict__ Ps,
                                              float* __restrict__ Fac, int gc){
  int rid = blockIdx.x * 4 + (threadIdx.x >> 6);
  int lane = threadIdx.x & 63;
  if (rid >= gc * HW) return;
  const float* pm = Pm + (size_t)rid * NBLK;
  const float* ps = Ps + (size_t)rid * NBLK;
  float mv = (lane < NBLK) ? pm[lane] : -3e38f;
  float sv = (lane < NBLK) ? ps[lane] : 0.f;
  float M = mv;
  #pragma unroll
  for (int o = 1; o < 64; o <<= 1) M = fmaxf(M, __shfl_xor(M, o));
  float e = (lane < NBLK) ? __expf(mv - M) : 0.f;
  float c = e * sv;
  #pragma unroll
  for (int o = 1; o < 64; o <<= 1) c += __shfl_xor(c, o);
  float inv = 1.f / c;
  if (lane < NBLK) Fac[(size_t)rid * NBLK + lane] = e * inv;
}

// GEMM2 (R13: BM=128, 8 waves 4mt x 3nt, K-split x2, 2-deep counted vmcnt,
// setprio, j-major 2-round epilogue). UNCHANGED.
__global__ __launch_bounds__(512) void k_gemm2n(const f16* __restrict__ S16, const f16* __restrict__ RpT,
    const float* __restrict__ Fac, h16* __restrict__ T, int b0){
  int nwg = gridDim.x;
  int p = blockIdx.x;
  int L = (nwg % 8 == 0) ? ((p & 7)*(nwg>>3) + (p>>3)) : p;
  int jh = L % 3; int t1 = L / 3; int my = t1 % 18; int t2 = t1 / 18;
  int ks = t2 & 1;  int bg = t2 >> 1;
  int b = b0 + bg;
  int m0 = my * 128;
  int tid = threadIdx.x, l = tid & 63, w = tid >> 6;
  int wm = w >> 2, wc = w & 3;
  int ch = l >> 4, cl = l & 15;
  __shared__ __align__(16) char smem[48640];
  f32x4 acc[4][3] = {};
  int lrm[4], abyte[4], rbyte[3];
  #pragma unroll
  for (int mt = 0; mt < 4; mt++){
    lrm[mt] = wm*64 + mt*16 + cl;
    abyte[mt] = lrm[mt]*64 + ((ch ^ ((lrm[mt]>>1)&3))<<4);
  }
  #pragma unroll
  for (int nt = 0; nt < 3; nt++){
    int jr = wc*48 + nt*16 + cl;
    rbyte[nt] = jr*64 + ((ch ^ ((jr>>1)&3))<<4);
  }
  const f16* Sb  = S16 + ((size_t)bg*HW + m0)*SW2;
  const f16* Rb0 = RpT + (size_t)b*((size_t)NT*576*32) + (size_t)jh*(192*32);
  const float* facb = Fac + ((size_t)bg*HW + m0)*NBLK;
  int nb0 = (ks*NT2) >> 2;

  auto STAGE = [&](int t, int bi){
    char* dS = smem + bi*8192;
    char* dR = smem + 16384 + bi*12288;
    const f16* Rb = Rb0 + (size_t)t*(576*32);
    {
      int row = tid >> 2, cs = (tid & 3) ^ ((row >> 1) & 3);
      gl16(Sb + (size_t)row*SW2 + t*32 + cs*8, dS + tid*16);
      gl16(Rb + (size_t)row*32 + cs*8, dR + tid*16);
    }
    if (tid < 256){
      int i2 = tid + 512;
      int r2 = i2 >> 2, c2 = (i2 & 3) ^ ((r2 >> 1) & 3);
      gl16(Rb + (size_t)r2*32 + c2*8, dR + i2*16);
    }
  };

  {
    f16* fl = (f16*)(smem + 40960);
    for (int i = tid; i < 30*128; i += 512){
      int nbl = i >> 7, mm = i & 127;
      int nb = nb0 + nbl;
      fl[i] = (nb < NBLK) ? (f16)facb[(size_t)mm*NBLK + nb] : (f16)0.f;
    }
  }
  STAGE(ks*NT2, 0);
  __syncthreads();

  int cur = 0;
  for (int tt = 0; tt < NT2; ++tt){
    int t = ks*NT2 + tt;
    if (tt + 1 < NT2){
      STAGE(t + 1, cur ^ 1);
      if (tid < 256) { asm volatile("s_waitcnt vmcnt(3)" ::: "memory"); }
      else           { asm volatile("s_waitcnt vmcnt(2)" ::: "memory"); }
    } else {
      asm volatile("s_waitcnt vmcnt(0)" ::: "memory");
    }
    __builtin_amdgcn_s_barrier();
    asm volatile("" ::: "memory");
    const char* Sc = smem + cur*8192;
    const char* Rc = smem + 16384 + cur*12288;
    const f16* fl = (const f16*)(smem + 40960);
    int nbl = (t >> 2) - nb0;
    __builtin_amdgcn_s_setprio(1);
    f16x8 pa[4];
    #pragma unroll
    for (int mt = 0; mt < 4; mt++){
      f16 fac = fl[nbl*128 + lrm[mt]];
      f16x8 sv = *reinterpret_cast<const f16x8*>(Sc + abyte[mt]);
      pa[mt] = sv * fac;
    }
    #pragma unroll
    for (int nt = 0; nt < 3; nt++){
      f16x8 bv = *reinterpret_cast<const f16x8*>(Rc + rbyte[nt]);
      #pragma unroll
      for (int mt = 0; mt < 4; mt++)
        acc[mt][nt] = __builtin_amdgcn_mfma_f32_16x16x32_f16(pa[mt], bv, acc[mt][nt], 0, 0, 0);
    }
    __builtin_amdgcn_s_setprio(0);
    asm volatile("s_waitcnt lgkmcnt(0)" ::: "memory");
    __builtin_amdgcn_s_barrier();
    cur ^= 1;
  }

  h16* Tsp = T + (size_t)ks * ((size_t)NB*576*HW);
  h16* Tl = (h16*)smem;
  #pragma unroll
  for (int r = 0; r < 2; ++r){
    __syncthreads();
    if ((wc >> 1) == r){
      #pragma unroll
      for (int nt = 0; nt < 3; nt++)
        #pragma unroll
        for (int mt = 0; mt < 4; mt++)
          #pragma unroll
          for (int i = 0; i < 4; i++)
            Tl[((wc & 1)*48 + nt*16 + cl)*136 + wm*64 + mt*16 + ch*4 + i] = __float2half(acc[mt][nt][i]);
    }
    __syncthreads();
    #pragma unroll
    for (int rep = 0; rep < 3; rep++){
      int idx = tid + rep*512;
      int j0 = idx >> 4, q = idx & 15;
      uint4 v = *reinterpret_cast<const uint4*>((const char*)Tl + j0*272 + q*16);
      h16* dst = Tsp + ((size_t)b*576 + jh*192 + r*96 + j0)*HW + m0 + q*8;
      *reinterpret_cast<uint4*>(dst) = v;
    }
  }
}

// out = raw_x + 0.25 * fold(T0+T1); raw input via flag.
__global__ __launch_bounds__(256) void k_fold(const h16* __restrict__ T, const void* __restrict__ xraw,
    void* __restrict__ out, const int* __restrict__ flag){
  const h16* T2 = T + (size_t)NB*576*HW;
  int id = blockIdx.x * 256 + threadIdx.x;
  if (id >= NB * 64 * HW) return;
  int f = flag[0];
  int b = id / (64*HW), id2 = id - b*(64*HW);
  int co = id2 / HW, p = id2 - co * HW;
  int y = p / 48, xx = p - y * 48;
  float acc = 0.f;
  #pragma unroll
  for (int dy = -1; dy <= 1; dy++){
    int yy = y + dy; if (yy < 0 || yy >= 48) continue;
    #pragma unroll
    for (int dx = -1; dx <= 1; dx++){
      int x2 = xx + dx; if (x2 < 0 || x2 >= 48) continue;
      int j = co*9 + (1-dy)*3 + (1-dx);
      size_t o = ((size_t)b*576 + j)*HW + yy*48 + x2;
      acc += __half2float(T[o]) + __half2float(T2[o]);
    }
  }
  size_t gi = (size_t)id;
  float r = ldf(xraw, gi, f) + 0.25f * acc;
  if (f) ((__hip_bfloat16*)out)[gi] = __float2bfloat16(r);
  else   ((float*)out)[gi] = r;
}

extern "C" void kernel_launch(void* const* d_in, const int* in_sizes, int n_in,
                              void* d_out, int out_size, void* d_ws, size_t ws_size,
                              hipStream_t stream){
  (void)out_size; (void)n_in;

  char* cur = (char*)d_ws;
  auto carve = [&](size_t bytes)->char*{
    char* p = cur; cur += (bytes + 255) & ~(size_t)255; return p;
  };
  int*     flag = (int*)    carve(4);
  ushort2* lut  = (ushort2*)carve((size_t)NP * 4);
  float* canon[9];
  for (int i = 0; i < 9; i++) canon[i] = (float*)carve((size_t)in_sizes[i+1] * 4);
  float* Wb = canon[0]; float* bb = canon[1]; float* ab = canon[2];
  float* Wm = canon[3]; float* bm = canon[4]; float* am = canon[5];
  float* Wa = canon[6]; float* ba = canon[7]; float* aa = canon[8];

  h16*   xs    = (h16*)  carve((size_t)NB * 64 * NP * 2);
  float* mbuf  = (float*)carve((size_t)NB * 32 * HW * 4);
  float* mat   = (float*)carve((size_t)NB * 32 * NP * 4);
  float* qbuf  = (float*)carve((size_t)NB * NP * 4);
  float* ninv  = (float*)carve((size_t)NB * NP * 4);
  h16*   baseh = (h16*)  carve((size_t)NB * 64 * NP * 2);
  h16*   U     = (h16*)  carve((size_t)NB * HW * 288 * 2);
  h16*   RpT   = (h16*)  carve((size_t)NB * NT * 576 * 32 * 2);
  h16*   T     = (h16*)  carve((size_t)2 * NB * 576 * HW * 2);

  size_t fixed = (size_t)(cur - (char*)d_ws);
  size_t perb  = (((size_t)NPAD*288*2 + 255) & ~(size_t)255)
               + (((size_t)HW*SW2*2 + 255) & ~(size_t)255)
               + 3 * (((size_t)HW*NBLK*4 + 255) & ~(size_t)255);
  size_t avail = (ws_size > fixed) ? ws_size - fixed : 0;
  int g = (int)(avail / perb);
  if (g < 1) g = 1;
  if (g > NB) g = NB;
  h16*   Wp  = (h16*)  carve((size_t)g * NPAD * 288 * 2);
  h16*   S16 = (h16*)  carve((size_t)g * HW * SW2 * 2);
  float* Pm  = (float*)carve((size_t)g * HW * NBLK * 4);
  float* Ps  = (float*)carve((size_t)g * HW * NBLK * 4);
  float* Fac = (float*)carve((size_t)g * HW * NBLK * 4);

  k_detect<<<1, 256, 0, stream>>>(d_in[0], flag);
  k_lut<<<(NP + 255)/256, 256, 0, stream>>>(lut);
  {
    CanonArgs ca; int tot = 0;
    for (int i = 0; i < 9; i++){
      ca.src[i] = d_in[i+1]; ca.dst[i] = canon[i];
      tot += in_sizes[i+1]; ca.end[i] = tot;
    }
    k_canon_all<<<(tot + 255)/256, 256, 0, stream>>>(ca, tot, flag);
  }

  k_resize<<<((size_t)NB*NCH*NP + 255)/256, 256, 0, stream>>>(d_in[0], flag, lut, xs);

  {
    ConvArgs ca;
    ca.W[0]=Wm; ca.bias[0]=bm; ca.alpha[0]=am; ca.out[0]=(void*)mat;   ca.npix[0]=NP; ca.cout[0]=32; ca.ob[0]=(size_t)32*NP; ca.rso[0]=NP; ca.of16[0]=0;
    ca.W[1]=Wa; ca.bias[1]=ba; ca.alpha[1]=aa; ca.out[1]=(void*)baseh; ca.npix[1]=NP; ca.cout[1]=64; ca.ob[1]=(size_t)64*NP; ca.rso[1]=NP; ca.of16[1]=1;
    ca.W[2]=Wb; ca.bias[2]=bb; ca.alpha[2]=ab; ca.out[2]=(void*)mbuf;  ca.npix[2]=HW; ca.cout[2]=32; ca.ob[2]=(size_t)32*HW; ca.rso[2]=HW; ca.of16[2]=0;
    dim3 gc3((NP + 63)/64, NB, 3);
    k_conv_all<<<gc3, 256, 0, stream>>>(xs, ca);
  }

  k_sq  <<<(NB*NP + 255)/256, 256, 0, stream>>>(mat, qbuf);
  k_ninv<<<(NB*NP + 255)/256, 256, 0, stream>>>(qbuf, ninv, lut);
  {
    long long tot = (long long)TOTU + (long long)NB*NT*576*32;
    k_packUR<<<(unsigned)((tot + 255)/256), 256, 0, stream>>>(mbuf, baseh, lut, U, RpT);
  }

  for (int b0 = 0; b0 < NB; b0 += g){
    int gc = (b0 + g <= NB) ? g : (NB - b0);
    k_packW<<<((size_t)gc*NPAD*288 + 255)/256, 256, 0, stream>>>(mat, ninv, lut, Wp, b0, gc);
    int nwg1 = 18 * NBLK * gc;
    k_gemm1m<<<nwg1, 256, 0, stream>>>((const f16*)U, (const f16*)Wp, S16, Pm, Ps, b0);
    k_sfac<<<(gc*HW + 3)/4, 256, 0, stream>>>(Pm, Ps, Fac, gc);
    int nwg2 = 3 * 18 * 2 * gc;
    k_gemm2n<<<nwg2, 512, 0, stream>>>((const f16*)S16, (const f16*)RpT, Fac, T, b0);
  }

  k_fold<<<(NB*64*HW + 255)/256, 256, 0, stream>>>(T, d_in[0], d_out, flag);
}

// Round 17
// 311.013 us; speedup vs baseline: 1.1023x; 1.1023x over previous
//
#include <hip/hip_runtime.h>
#include <hip/hip_bf16.h>
#include <hip/hip_fp16.h>

typedef __half h16;
typedef _Float16 f16;
typedef f16 f16x8 __attribute__((ext_vector_type(8)));
typedef __attribute__((ext_vector_type(4))) float f32x4;

#define NB 4
#define NCH 64
#define HW 2304      // 48*48
#define NP 7470      // total patches across 5 scales
#define NPAD 7552    // 59*128 = 236*32
#define NT 236       // k-tiles of 32
#define NT2 118      // per K-split half
#define NBLK 59      // 128-col blocks
#define SW2 NPAD
#define TOTU (NB*HW*288)

__device__ __forceinline__ float us2f(unsigned short u){
  unsigned v = (unsigned)u << 16; float f; __builtin_memcpy(&f, &v, 4); return f;
}
__device__ __forceinline__ float ldf(const void* p, size_t i, int f){
  return f ? us2f(((const unsigned short*)p)[i]) : ((const float*)p)[i];
}
__device__ __forceinline__ void gl16(const void* g, void* l){
  __builtin_amdgcn_global_load_lds((const __attribute__((address_space(1))) unsigned int*)g,
                                   (__attribute__((address_space(3))) unsigned int*)l, 16, 0, 0);
}

// full decode (divides) — used ONLY by k_lut
__device__ __forceinline__ void n_decode(int n, int& off, int& d, int& y, int& x){
  if (n < 2304)      { off = 0;    d = 48; }
  else if (n < 4153) { off = 2304; d = 43; }
  else if (n < 5597) { off = 4153; d = 38; }
  else if (n < 6686) { off = 5597; d = 33; }
  else               { off = 6686; d = 28; }
  int l = n - off; y = l / d; x = l - y * d;
}
// div-free range lookup
__device__ __forceinline__ void n_range(int n, int& off, int& d){
  if (n < 2304)      { off = 0;    d = 48; }
  else if (n < 4153) { off = 2304; d = 43; }
  else if (n < 5597) { off = 4153; d = 38; }
  else if (n < 6686) { off = 5597; d = 33; }
  else               { off = 6686; d = 28; }
}

// ---- LUT: lut[n] = (y, x) ----
__global__ __launch_bounds__(256) void k_lut(ushort2* __restrict__ lut){
  int n = blockIdx.x * 256 + threadIdx.x;
  if (n >= NP) return;
  int off, d, y, x; n_decode(n, off, d, y, x);
  lut[n] = make_ushort2((unsigned short)y, (unsigned short)x);
}

// ---- dtype probe (proven R3-R16) ----
__global__ __launch_bounds__(256) void k_detect(const void* __restrict__ x, int* __restrict__ flag){
  const unsigned short* u = (const unsigned short*)x;
  int tid = threadIdx.x;
  int c = 0;
  for (int i = tid; i < 8192; i += 256){
    float v = us2f(u[i]);
    float a = fabsf(v);
    if (v == 0.f || (a > 1e-5f && a < 1e3f)) c++;
  }
  #pragma unroll
  for (int o = 1; o < 64; o <<= 1) c += __shfl_xor(c, o);
  __shared__ int wr[4];
  if ((tid & 63) == 0) wr[tid >> 6] = c;
  __syncthreads();
  if (tid == 0) flag[0] = ((wr[0]+wr[1]+wr[2]+wr[3]) > 7000) ? 1 : 0;
}

struct CanonArgs { const void* src[9]; float* dst[9]; int end[9]; };

__global__ __launch_bounds__(256) void k_canon_all(CanonArgs a, int tot, const int* __restrict__ flag){
  int id = blockIdx.x * 256 + threadIdx.x;
  if (id >= tot) return;
  int k = 0;
  while (id >= a.end[k]) k++;
  int local = id - (k ? a.end[k-1] : 0);
  float v;
  if (flag[0]) v = us2f(((const unsigned short*)a.src[k])[local]);
  else         v = ((const float*)a.src[k])[local];
  a.dst[k][local] = v;
}

// Bilinear resize from RAW x (flag-dispatched dtype): xs f16 [b][c][n]
__global__ __launch_bounds__(256) void k_resize(const void* __restrict__ xraw, const int* __restrict__ flag,
                                                const ushort2* __restrict__ lut, h16* __restrict__ xs){
  int id = blockIdx.x * 256 + threadIdx.x;
  if (id >= NB * NCH * NP) return;
  int f = flag[0];
  int b = id / (NCH*NP), rem = id - b*(NCH*NP);
  int c = rem / NP, n = rem - c*NP;
  int off, d; n_range(n, off, d);
  ushort2 yx = lut[n];
  int y = yx.x, xx = yx.y;
  size_t base = ((size_t)b * NCH + c) * HW;
  float v;
  if (off == 0){
    v = ldf(xraw, base + y*48 + xx, f);
  } else {
    float cy = (y + 0.5f) * (48.0f / (float)d) - 0.5f;
    float cx = (xx + 0.5f) * (48.0f / (float)d) - 0.5f;
    int y0 = (int)floorf(cy), x0 = (int)floorf(cx);
    float fy = cy - (float)y0, fx = cx - (float)x0;
    int y1 = min(y0 + 1, 47), x1 = min(x0 + 1, 47);
    y0 = max(y0, 0); x0 = max(x0, 0);
    v = (1.f-fy)*((1.f-fx)*ldf(xraw, base + y0*48+x0, f) + fx*ldf(xraw, base + y0*48+x1, f))
      + fy*((1.f-fx)*ldf(xraw, base + y1*48+x0, f) + fx*ldf(xraw, base + y1*48+x1, f));
  }
  xs[id] = __float2half(v);
}

// All three 1x1 convs in one launch; z selects {mat, baseh, mbuf}.
struct ConvArgs {
  const float* W[3]; const float* bias[3]; const float* alpha[3];
  void* out[3]; int npix[3]; int cout[3]; size_t ob[3]; int rso[3]; int of16[3];
};
__global__ __launch_bounds__(256) void k_conv_all(const h16* __restrict__ xs, ConvArgs ca){
  int z = blockIdx.z;
  int npix = ca.npix[z], cout = ca.cout[z];
  int n0 = blockIdx.x * 64;
  if (n0 >= npix) return;
  __shared__ float Wl[64*64];
  __shared__ float it[64][64];
  int b = blockIdx.y;
  int tid = threadIdx.x;
  const h16* ib = xs + (size_t)b * (64*NP);
  const float* Wt = ca.W[z];
  for (int i = tid; i < cout * 64; i += 256) Wl[i] = Wt[i];
  for (int i = tid; i < 64 * 64; i += 256){
    int ci = i >> 6, nn = i & 63;
    int n = n0 + nn;
    it[ci][nn] = (n < npix) ? __half2float(ib[(size_t)ci * NP + n]) : 0.f;
  }
  __syncthreads();
  float al = ca.alpha[z][0];
  const float* bias = ca.bias[z];
  for (int oi = tid; oi < cout * 64; oi += 256){
    int co = oi >> 6, nn = oi & 63;
    float acc = bias[co];
    #pragma unroll
    for (int ci = 0; ci < 64; ci++) acc = fmaf(Wl[co*64+ci], it[ci][nn], acc);
    acc = acc >= 0.f ? acc : al * acc;
    int n = n0 + nn;
    if (n < npix){
      size_t idx = (size_t)b * ca.ob[z] + (size_t)co * ca.rso[z] + n;
      if (ca.of16[z]) ((h16*)ca.out[z])[idx] = __float2half(acc);
      else            ((float*)ca.out[z])[idx] = acc;
    }
  }
}

// pass 1: q[b][n] = sum_c mat[c][n]^2
__global__ __launch_bounds__(256) void k_sq(const float* __restrict__ mat, float* __restrict__ q){
  int id = blockIdx.x * 256 + threadIdx.x;
  if (id >= NB * NP) return;
  int b = id / NP, n = id - b * NP;
  const float* mp = mat + (size_t)b * 32 * NP + n;
  float s = 0.f;
  #pragma unroll
  for (int c = 0; c < 32; c++){ float v = mp[(size_t)c * NP]; s += v * v; }
  q[id] = s;
}

// pass 2: ninv[b][n] = 1/max(sqrt(9-tap sum of q), 1e-4); LUT decode
__global__ __launch_bounds__(256) void k_ninv(const float* __restrict__ q, float* __restrict__ ninv,
                                              const ushort2* __restrict__ lut){
  int id = blockIdx.x * 256 + threadIdx.x;
  if (id >= NB * NP) return;
  int b = id / NP, n = id - b * NP;
  int off, d; n_range(n, off, d);
  ushort2 yx = lut[n];
  int y = yx.x, x = yx.y;
  const float* qb = q + (size_t)b * NP + off;
  float s = 0.f;
  #pragma unroll
  for (int dy = -1; dy <= 1; dy++){
    int yy = y + dy; if (yy < 0 || yy >= d) continue;
    #pragma unroll
    for (int dx = -1; dx <= 1; dx++){
      int xx = x + dx; if (xx < 0 || xx >= d) continue;
      s += qb[yy * d + xx];
    }
  }
  ninv[id] = 1.f / fmaxf(sqrtf(s), 1e-4f);
}

// fused packU + packR (id-partitioned); LUT decode in packR.
__global__ __launch_bounds__(256) void k_packUR(const float* __restrict__ mbuf, const h16* __restrict__ baseh,
    const ushort2* __restrict__ lut, h16* __restrict__ U, h16* __restrict__ RpT){
  int id = blockIdx.x * 256 + threadIdx.x;
  if (id < TOTU){
    int b = id / (HW*288), rem = id - b*(HW*288);
    int p = rem / 288, k = rem - p * 288;
    int c = k / 9, r = k - c * 9, kh = r / 3, kw = r - kh * 3;
    int y = p / 48 + kh - 1, x = (p % 48) + kw - 1;
    float v = 0.f;
    if (y >= 0 && y < 48 && x >= 0 && x < 48)
      v = mbuf[((size_t)b * 32 + c) * HW + y * 48 + x];
    U[id] = __float2half(v);
    return;
  }
  int id2 = id - TOTU;
  if (id2 >= NB * NT * 576 * 32) return;
  int b = id2 / (NT*576*32), rem = id2 - b*(NT*576*32);
  int t = rem / (576*32), rem2 = rem - t*(576*32);
  int j = rem2 / 32, kl = rem2 - j*32;
  int n = t*32 + kl;
  h16 v = __float2half(0.f);
  if (n < NP){
    int c = j / 9, r = j - c * 9, kh = r / 3, kw = r - kh * 3;
    int off, d; n_range(n, off, d);
    ushort2 yx = lut[n];
    int yy = (int)yx.x + kh - 1, xx = (int)yx.y + kw - 1;
    if (yy >= 0 && yy < d && xx >= 0 && xx < d)
      v = baseh[((size_t)b * 64 + c) * NP + off + yy * d + xx];
  }
  RpT[id2] = v;
}

// unfold mat * (10*ninv) -> Wp[g][NPAD][288] f16; LUT decode
__global__ __launch_bounds__(256) void k_packW(const float* __restrict__ mat, const float* __restrict__ ninv,
                                               const ushort2* __restrict__ lut, h16* __restrict__ Wp, int b0, int g){
  int id = blockIdx.x * 256 + threadIdx.x;
  if (id >= g * NPAD * 288) return;
  int bg = id / (NPAD*288), rem = id - bg*(NPAD*288);
  int n = rem / 288, k = rem - n * 288;
  float v = 0.f;
  if (n < NP){
    int b = b0 + bg;
    int c = k / 9, r = k - c * 9, kh = r / 3, kw = r - kh * 3;
    int off, d; n_range(n, off, d);
    ushort2 yx = lut[n];
    int yy = (int)yx.x + kh - 1, xx = (int)yx.y + kw - 1;
    if (yy >= 0 && yy < d && xx >= 0 && xx < d)
      v = mat[((size_t)b * 32 + c) * NP + off + yy * d + xx] * 10.f * ninv[(size_t)b*NP + n];
  }
  Wp[id] = __float2half(v);
}

// GEMM1 + fused block-local softmax stats (R14/R15-proven 512-thr version:
// 8 waves 2wm x 2wn, wave 32x64 = 2mt x 4nt; 3-deep vmcnt(4); XCD-chunked
// 1D grid; setprio; LDS-staged coalesced S16 epilogue).
__global__ __launch_bounds__(512) void k_gemm1m(const f16* __restrict__ U, const f16* __restrict__ Wp,
    h16* __restrict__ S16, float* __restrict__ Pm, float* __restrict__ Ps, int b0){
  int nwg = gridDim.x;
  int p = blockIdx.x;
  int qc = nwg >> 3, rc = nwg & 7, xcd = p & 7;
  int L = (xcd < rc ? xcd*(qc+1) : rc*(qc+1) + (xcd - rc)*qc) + (p >> 3);
  int my = L % 18; int t1 = L / 18; int nb = t1 % NBLK; int bg = t1 / NBLK;
  int b = b0 + bg;
  int m0 = my * 128, n0 = nb * 128;
  int tid = threadIdx.x, l = tid & 63, w = tid >> 6;
  int wm = w >> 1, wn = w & 1;
  int ch = l >> 4, cl = l & 15;
  __shared__ __align__(16) char smem[51200];
  // At[t]=smem+t*8192 (t<3); Bt[t]=smem+24576+t*8192; mred@49152; sred@50176.
  // Epilogue: Tl (h16 [128][132]) aliases smem+0 (33792B <= 49152).
  float* mredp = (float*)(smem + 49152);
  float* sredp = (float*)(smem + 50176);
  f32x4 acc[2][4] = {};
  const f16* Ub = U + ((size_t)b * HW + m0) * 288;
  const f16* Wb = Wp + ((size_t)bg * NPAD + n0) * 288;
  int abyte[2], bbyte[4];
  #pragma unroll
  for (int mt = 0; mt < 2; mt++){
    int lr = wm*32 + mt*16 + cl;
    abyte[mt] = lr*64 + ((ch ^ ((lr>>1)&3))<<4);
  }
  #pragma unroll
  for (int nt = 0; nt < 4; nt++){
    int lr = wn*64 + nt*16 + cl;
    bbyte[nt] = lr*64 + ((ch ^ ((lr>>1)&3))<<4);
  }
  int srow = tid >> 2, scs = (tid & 3) ^ ((srow >> 1) & 3);
  auto STAGE1 = [&](int t, int bi){
    gl16(Ub + (size_t)srow*288 + t*32 + scs*8, smem + bi*8192 + tid*16);
    gl16(Wb + (size_t)srow*288 + t*32 + scs*8, smem + 24576 + bi*8192 + tid*16);
  };
  STAGE1(0, 0);
  STAGE1(1, 1);
  __syncthreads();
  int cur = 0;
  for (int t = 0; t < 9; ++t){
    int nx = cur + 2; if (nx >= 3) nx -= 3;
    if (t + 2 < 9){
      STAGE1(t + 2, nx);
      asm volatile("s_waitcnt vmcnt(4)" ::: "memory");
    } else if (t + 1 < 9){
      asm volatile("s_waitcnt vmcnt(2)" ::: "memory");
    } else {
      asm volatile("s_waitcnt vmcnt(0)" ::: "memory");
    }
    __builtin_amdgcn_s_barrier();
    asm volatile("" ::: "memory");
    const char* Ac = smem + cur*8192;
    const char* Bc = smem + 24576 + cur*8192;
    __builtin_amdgcn_s_setprio(1);
    f16x8 a[2], bv[4];
    #pragma unroll
    for (int mt = 0; mt < 2; mt++) a[mt] = *reinterpret_cast<const f16x8*>(Ac + abyte[mt]);
    #pragma unroll
    for (int nt = 0; nt < 4; nt++) bv[nt] = *reinterpret_cast<const f16x8*>(Bc + bbyte[nt]);
    #pragma unroll
    for (int mt = 0; mt < 2; mt++)
      #pragma unroll
      for (int nt = 0; nt < 4; nt++)
        acc[mt][nt] = __builtin_amdgcn_mfma_f32_16x16x32_f16(a[mt], bv[nt], acc[mt][nt], 0, 0, 0);
    __builtin_amdgcn_s_setprio(0);
    asm volatile("s_waitcnt lgkmcnt(0)" ::: "memory");
    __builtin_amdgcn_s_barrier();
    cur = cur + 1; if (cur >= 3) cur -= 3;
  }
  // phase A: block-local row max over the 128 cols
  #pragma unroll
  for (int mt = 0; mt < 2; mt++)
    #pragma unroll
    for (int i = 0; i < 4; i++){
      float v = -3e38f;
      #pragma unroll
      for (int nt = 0; nt < 4; nt++){
        int gn = n0 + wn*64 + nt*16 + cl;
        float t = acc[mt][nt][i];
        v = fmaxf(v, (gn < NP) ? t : -3e38f);
      }
      v = fmaxf(v, __shfl_xor(v, 1));
      v = fmaxf(v, __shfl_xor(v, 2));
      v = fmaxf(v, __shfl_xor(v, 4));
      v = fmaxf(v, __shfl_xor(v, 8));
      if (cl == 0) mredp[(wm*32 + mt*16 + ch*4 + i)*2 + wn] = v;
    }
  __syncthreads();
  // phase B: exp into LDS tile (aliases At/Bt), row sums
  {
    h16* Tl = (h16*)smem;
    #pragma unroll
    for (int mt = 0; mt < 2; mt++)
      #pragma unroll
      for (int i = 0; i < 4; i++){
        int r = wm*32 + mt*16 + ch*4 + i;
        float Ml = fmaxf(mredp[r*2+0], mredp[r*2+1]);
        float s = 0.f;
        #pragma unroll
        for (int nt = 0; nt < 4; nt++){
          int c = wn*64 + nt*16 + cl;
          int gn = n0 + c;
          float e = (gn < NP) ? __expf(acc[mt][nt][i] - Ml) : 0.f;
          Tl[r*132 + c] = __float2half(e);
          s += e;
        }
        s += __shfl_xor(s, 1);
        s += __shfl_xor(s, 2);
        s += __shfl_xor(s, 4);
        s += __shfl_xor(s, 8);
        if (cl == 0) sredp[r*2 + wn] = s;
      }
  }
  __syncthreads();
  // phase C: stats out
  if (tid < 128){
    float Mf = fmaxf(mredp[tid*2+0], mredp[tid*2+1]);
    float Lg = sredp[tid*2+0] + sredp[tid*2+1];
    size_t o = ((size_t)bg*HW + m0 + tid)*NBLK + nb;
    Pm[o] = Mf; Ps[o] = Lg;
  }
  // phase D: coalesced S16 write, 128 rows x 256B; 2048 uint4 / 512 thr
  {
    const h16* Tl = (const h16*)smem;
    #pragma unroll
    for (int rep = 0; rep < 4; rep++){
      int idx = tid + rep*512;
      int j0 = idx >> 4, qq = idx & 15;
      uint4 v = *reinterpret_cast<const uint4*>((const char*)Tl + j0*264 + qq*16);
      h16* dst = S16 + ((size_t)bg*HW + m0 + j0)*SW2 + n0 + qq*8;
      *reinterpret_cast<uint4*>(dst) = v;
    }
  }
}

// combine partials (wave per row): Fac[bg][m][k] = exp(Mloc-Mglob)/L_glob
__global__ __launch_bounds__(256) void k_sfac(const float* __restrict__ Pm, const float* __restrict__ Ps,
                                              float* __restrict__ Fac, int gc){
  int rid = blockIdx.x * 4 + (threadIdx.x >> 6);
  int lane = threadIdx.x & 63;
  if (rid >= gc * HW) return;
  const float* pm = Pm + (size_t)rid * NBLK;
  const float* ps = Ps + (size_t)rid * NBLK;
  float mv = (lane < NBLK) ? pm[lane] : -3e38f;
  float sv = (lane < NBLK) ? ps[lane] : 0.f;
  float M = mv;
  #pragma unroll
  for (int o = 1; o < 64; o <<= 1) M = fmaxf(M, __shfl_xor(M, o));
  float e = (lane < NBLK) ? __expf(mv - M) : 0.f;
  float c = e * sv;
  #pragma unroll
  for (int o = 1; o < 64; o <<= 1) c += __shfl_xor(c, o);
  float inv = 1.f / c;
  if (lane < NBLK) Fac[(size_t)rid * NBLK + lane] = e * inv;
}

// GEMM2 (R13-proven: BM=128, 8 waves 4mt x 3nt, K-split x2, 2-deep counted
// vmcnt, setprio, j-major 2-round epilogue). UNCHANGED.
__global__ __launch_bounds__(512) void k_gemm2n(const f16* __restrict__ S16, const f16* __restrict__ RpT,
    const float* __restrict__ Fac, h16* __restrict__ T, int b0){
  int nwg = gridDim.x;
  int p = blockIdx.x;
  int L = (nwg % 8 == 0) ? ((p & 7)*(nwg>>3) + (p>>3)) : p;
  int jh = L % 3; int t1 = L / 3; int my = t1 % 18; int t2 = t1 / 18;
  int ks = t2 & 1;  int bg = t2 >> 1;
  int b = b0 + bg;
  int m0 = my * 128;
  int tid = threadIdx.x, l = tid & 63, w = tid >> 6;
  int wm = w >> 2, wc = w & 3;
  int ch = l >> 4, cl = l & 15;
  __shared__ __align__(16) char smem[48640];
  f32x4 acc[4][3] = {};
  int lrm[4], abyte[4], rbyte[3];
  #pragma unroll
  for (int mt = 0; mt < 4; mt++){
    lrm[mt] = wm*64 + mt*16 + cl;
    abyte[mt] = lrm[mt]*64 + ((ch ^ ((lrm[mt]>>1)&3))<<4);
  }
  #pragma unroll
  for (int nt = 0; nt < 3; nt++){
    int jr = wc*48 + nt*16 + cl;
    rbyte[nt] = jr*64 + ((ch ^ ((jr>>1)&3))<<4);
  }
  const f16* Sb  = S16 + ((size_t)bg*HW + m0)*SW2;
  const f16* Rb0 = RpT + (size_t)b*((size_t)NT*576*32) + (size_t)jh*(192*32);
  const float* facb = Fac + ((size_t)bg*HW + m0)*NBLK;
  int nb0 = (ks*NT2) >> 2;

  auto STAGE = [&](int t, int bi){
    char* dS = smem + bi*8192;
    char* dR = smem + 16384 + bi*12288;
    const f16* Rb = Rb0 + (size_t)t*(576*32);
    {
      int row = tid >> 2, cs = (tid & 3) ^ ((row >> 1) & 3);
      gl16(Sb + (size_t)row*SW2 + t*32 + cs*8, dS + tid*16);
      gl16(Rb + (size_t)row*32 + cs*8, dR + tid*16);
    }
    if (tid < 256){
      int i2 = tid + 512;
      int r2 = i2 >> 2, c2 = (i2 & 3) ^ ((r2 >> 1) & 3);
      gl16(Rb + (size_t)r2*32 + c2*8, dR + i2*16);
    }
  };

  {
    f16* fl = (f16*)(smem + 40960);
    for (int i = tid; i < 30*128; i += 512){
      int nbl = i >> 7, mm = i & 127;
      int nb = nb0 + nbl;
      fl[i] = (nb < NBLK) ? (f16)facb[(size_t)mm*NBLK + nb] : (f16)0.f;
    }
  }
  STAGE(ks*NT2, 0);
  __syncthreads();

  int cur = 0;
  for (int tt = 0; tt < NT2; ++tt){
    int t = ks*NT2 + tt;
    if (tt + 1 < NT2){
      STAGE(t + 1, cur ^ 1);
      if (tid < 256) { asm volatile("s_waitcnt vmcnt(3)" ::: "memory"); }
      else           { asm volatile("s_waitcnt vmcnt(2)" ::: "memory"); }
    } else {
      asm volatile("s_waitcnt vmcnt(0)" ::: "memory");
    }
    __builtin_amdgcn_s_barrier();
    asm volatile("" ::: "memory");
    const char* Sc = smem + cur*8192;
    const char* Rc = smem + 16384 + cur*12288;
    const f16* fl = (const f16*)(smem + 40960);
    int nbl = (t >> 2) - nb0;
    __builtin_amdgcn_s_setprio(1);
    f16x8 pa[4];
    #pragma unroll
    for (int mt = 0; mt < 4; mt++){
      f16 fac = fl[nbl*128 + lrm[mt]];
      f16x8 sv = *reinterpret_cast<const f16x8*>(Sc + abyte[mt]);
      pa[mt] = sv * fac;
    }
    #pragma unroll
    for (int nt = 0; nt < 3; nt++){
      f16x8 bv = *reinterpret_cast<const f16x8*>(Rc + rbyte[nt]);
      #pragma unroll
      for (int mt = 0; mt < 4; mt++)
        acc[mt][nt] = __builtin_amdgcn_mfma_f32_16x16x32_f16(pa[mt], bv, acc[mt][nt], 0, 0, 0);
    }
    __builtin_amdgcn_s_setprio(0);
    asm volatile("s_waitcnt lgkmcnt(0)" ::: "memory");
    __builtin_amdgcn_s_barrier();
    cur ^= 1;
  }

  h16* Tsp = T + (size_t)ks * ((size_t)NB*576*HW);
  h16* Tl = (h16*)smem;
  #pragma unroll
  for (int r = 0; r < 2; ++r){
    __syncthreads();
    if ((wc >> 1) == r){
      #pragma unroll
      for (int nt = 0; nt < 3; nt++)
        #pragma unroll
        for (int mt = 0; mt < 4; mt++)
          #pragma unroll
          for (int i = 0; i < 4; i++)
            Tl[((wc & 1)*48 + nt*16 + cl)*136 + wm*64 + mt*16 + ch*4 + i] = __float2half(acc[mt][nt][i]);
    }
    __syncthreads();
    #pragma unroll
    for (int rep = 0; rep < 3; rep++){
      int idx = tid + rep*512;
      int j0 = idx >> 4, q = idx & 15;
      uint4 v = *reinterpret_cast<const uint4*>((const char*)Tl + j0*272 + q*16);
      h16* dst = Tsp + ((size_t)b*576 + jh*192 + r*96 + j0)*HW + m0 + q*8;
      *reinterpret_cast<uint4*>(dst) = v;
    }
  }
}

// out = raw_x + 0.25 * fold(T0+T1); raw input via flag.
__global__ __launch_bounds__(256) void k_fold(const h16* __restrict__ T, const void* __restrict__ xraw,
    void* __restrict__ out, const int* __restrict__ flag){
  const h16* T2 = T + (size_t)NB*576*HW;
  int id = blockIdx.x * 256 + threadIdx.x;
  if (id >= NB * 64 * HW) return;
  int f = flag[0];
  int b = id / (64*HW), id2 = id - b*(64*HW);
  int co = id2 / HW, p = id2 - co * HW;
  int y = p / 48, xx = p - y * 48;
  float acc = 0.f;
  #pragma unroll
  for (int dy = -1; dy <= 1; dy++){
    int yy = y + dy; if (yy < 0 || yy >= 48) continue;
    #pragma unroll
    for (int dx = -1; dx <= 1; dx++){
      int x2 = xx + dx; if (x2 < 0 || x2 >= 48) continue;
      int j = co*9 + (1-dy)*3 + (1-dx);
      size_t o = ((size_t)b*576 + j)*HW + yy*48 + x2;
      acc += __half2float(T[o]) + __half2float(T2[o]);
    }
  }
  size_t gi = (size_t)id;
  float r = ldf(xraw, gi, f) + 0.25f * acc;
  if (f) ((__hip_bfloat16*)out)[gi] = __float2bfloat16(r);
  else   ((float*)out)[gi] = r;
}

extern "C" void kernel_launch(void* const* d_in, const int* in_sizes, int n_in,
                              void* d_out, int out_size, void* d_ws, size_t ws_size,
                              hipStream_t stream){
  (void)out_size; (void)n_in;

  char* cur = (char*)d_ws;
  auto carve = [&](size_t bytes)->char*{
    char* p = cur; cur += (bytes + 255) & ~(size_t)255; return p;
  };
  int*     flag = (int*)    carve(4);
  ushort2* lut  = (ushort2*)carve((size_t)NP * 4);
  float* canon[9];
  for (int i = 0; i < 9; i++) canon[i] = (float*)carve((size_t)in_sizes[i+1] * 4);
  float* Wb = canon[0]; float* bb = canon[1]; float* ab = canon[2];
  float* Wm = canon[3]; float* bm = canon[4]; float* am = canon[5];
  float* Wa = canon[6]; float* ba = canon[7]; float* aa = canon[8];

  h16*   xs    = (h16*)  carve((size_t)NB * 64 * NP * 2);
  float* mbuf  = (float*)carve((size_t)NB * 32 * HW * 4);
  float* mat   = (float*)carve((size_t)NB * 32 * NP * 4);
  float* qbuf  = (float*)carve((size_t)NB * NP * 4);
  float* ninv  = (float*)carve((size_t)NB * NP * 4);
  h16*   baseh = (h16*)  carve((size_t)NB * 64 * NP * 2);
  h16*   U     = (h16*)  carve((size_t)NB * HW * 288 * 2);
  h16*   RpT   = (h16*)  carve((size_t)NB * NT * 576 * 32 * 2);
  h16*   T     = (h16*)  carve((size_t)2 * NB * 576 * HW * 2);

  size_t fixed = (size_t)(cur - (char*)d_ws);
  size_t perb  = (((size_t)NPAD*288*2 + 255) & ~(size_t)255)
               + (((size_t)HW*SW2*2 + 255) & ~(size_t)255)
               + 3 * (((size_t)HW*NBLK*4 + 255) & ~(size_t)255);
  size_t avail = (ws_size > fixed) ? ws_size - fixed : 0;
  int g = (int)(avail / perb);
  if (g < 1) g = 1;
  if (g > NB) g = NB;
  h16*   Wp  = (h16*)  carve((size_t)g * NPAD * 288 * 2);
  h16*   S16 = (h16*)  carve((size_t)g * HW * SW2 * 2);
  float* Pm  = (float*)carve((size_t)g * HW * NBLK * 4);
  float* Ps  = (float*)carve((size_t)g * HW * NBLK * 4);
  float* Fac = (float*)carve((size_t)g * HW * NBLK * 4);

  k_detect<<<1, 256, 0, stream>>>(d_in[0], flag);
  k_lut<<<(NP + 255)/256, 256, 0, stream>>>(lut);
  {
    CanonArgs ca; int tot = 0;
    for (int i = 0; i < 9; i++){
      ca.src[i] = d_in[i+1]; ca.dst[i] = canon[i];
      tot += in_sizes[i+1]; ca.end[i] = tot;
    }
    k_canon_all<<<(tot + 255)/256, 256, 0, stream>>>(ca, tot, flag);
  }

  k_resize<<<((size_t)NB*NCH*NP + 255)/256, 256, 0, stream>>>(d_in[0], flag, lut, xs);

  {
    ConvArgs ca;
    ca.W[0]=Wm; ca.bias[0]=bm; ca.alpha[0]=am; ca.out[0]=(void*)mat;   ca.npix[0]=NP; ca.cout[0]=32; ca.ob[0]=(size_t)32*NP; ca.rso[0]=NP; ca.of16[0]=0;
    ca.W[1]=Wa; ca.bias[1]=ba; ca.alpha[1]=aa; ca.out[1]=(void*)baseh; ca.npix[1]=NP; ca.cout[1]=64; ca.ob[1]=(size_t)64*NP; ca.rso[1]=NP; ca.of16[1]=1;
    ca.W[2]=Wb; ca.bias[2]=bb; ca.alpha[2]=ab; ca.out[2]=(void*)mbuf;  ca.npix[2]=HW; ca.cout[2]=32; ca.ob[2]=(size_t)32*HW; ca.rso[2]=HW; ca.of16[2]=0;
    dim3 gc3((NP + 63)/64, NB, 3);
    k_conv_all<<<gc3, 256, 0, stream>>>(xs, ca);
  }

  k_sq  <<<(NB*NP + 255)/256, 256, 0, stream>>>(mat, qbuf);
  k_ninv<<<(NB*NP + 255)/256, 256, 0, stream>>>(qbuf, ninv, lut);
  {
    long long tot = (long long)TOTU + (long long)NB*NT*576*32;
    k_packUR<<<(unsigned)((tot + 255)/256), 256, 0, stream>>>(mbuf, baseh, lut, U, RpT);
  }

  for (int b0 = 0; b0 < NB; b0 += g){
    int gc = (b0 + g <= NB) ? g : (NB - b0);
    k_packW<<<((size_t)gc*NPAD*288 + 255)/256, 256, 0, stream>>>(mat, ninv, lut, Wp, b0, gc);
    int nwg1 = 18 * NBLK * gc;
    k_gemm1m<<<nwg1, 512, 0, stream>>>((const f16*)U, (const f16*)Wp, S16, Pm, Ps, b0);
    k_sfac<<<(gc*HW + 3)/4, 256, 0, stream>>>(Pm, Ps, Fac, gc);
    int nwg2 = 3 * 18 * 2 * gc;
    k_gemm2n<<<nwg2, 512, 0, stream>>>((const f16*)S16, (const f16*)RpT, Fac, T, b0);
  }

  k_fold<<<(NB*64*HW + 255)/256, 256, 0, stream>>>(T, d_in[0], d_out, flag);
}